// Round 16
// baseline (2939.425 us; speedup 1.0000x reference)
//
#include <hip/hip_runtime.h>
#include <stdint.h>

#pragma clang fp contract(off)

constexpr int B_ = 1024, IN_ = 2048, H0_ = 1024, H1_ = 1024, OUT_ = 512;
constexpr int TC = 2;        // timesteps per chunk
constexpr int NCHUNK = 8;    // 16 / TC
constexpr int GEMM_Q = 512;  // K-panel width under test: OpenBLAS ZEN retune / BLIS-AOCL KC

// Arithmetic fence: forces the f32 value to materialize — kills FMA contraction
// and reassociation across this point even under -ffp-contract=fast.
static __device__ __forceinline__ float fencef(float x) {
  asm volatile("" : "+v"(x));
  return x;
}

// ---------- transpose chunk: X[b][i][t0+tc] -> Xt[tc*B + b][i] (f32) ----------
__global__ void transpose_x2(const float* __restrict__ X, float* __restrict__ Xt, int t0) {
  int idx = blockIdx.x * 256 + threadIdx.x;  // b*IN + i
  int b = idx >> 11, i = idx & (IN_ - 1);
  float2 v = *(const float2*)(X + (size_t)idx * 16 + t0);
  Xt[(size_t)b * IN_ + i] = v.x;
  Xt[(size_t)(B_ + b) * IN_ + i] = v.y;
}

// ---------- f32 NT GEMM, BLAS-panel summation order, Q=512 ----------
// C[M][N] = A[M][K] @ B[N][K]^T, per element:
//  - K split into panels of 512 (clean: 2048=4x512, 1024=2x512)
//  - within a panel: ONE accumulator, ascending k, f32 FMA (product unrounded)
//  - across panels: left-associative f32 adds (beta=0 first panel == add to 0)
// Panel boundaries as bitmasks over 16-wide k-blocks.
// BM=128, BN=64, BK=16; 256 threads; 8x4 micro-tile.
__global__ __launch_bounds__(256) void gemm_obs(
    const float* __restrict__ A, const float* __restrict__ Bw,
    float* __restrict__ C, int Ntiles, int K, int N,
    unsigned long long pm0, unsigned long long pm1) {
  __shared__ float As[16][132];  // k-major, padded
  __shared__ float Bs[16][68];

  // bijective XCD swizzle (all grids here are multiples of 8)
  int bid = blockIdx.x, cpx = gridDim.x >> 3;
  int wg = (bid & 7) * cpx + (bid >> 3);
  int bm = wg / Ntiles, bn = wg - bm * Ntiles;

  int tid = threadIdx.x;
  int ra = tid >> 1, ca = (tid & 1) * 8;   // A staging: row 0..127, col-oct
  int rb = tid >> 2, cb = (tid & 3) * 4;   // B staging: row 0..63, col-quad
  int tx = tid & 15, ty = tid >> 4;        // micro-tile: cols tx*4.., rows ty*8..

  float creg[8][4] = {};   // running C (sum of completed panels)
  float pacc[8][4] = {};   // current-panel accumulator
  const size_t rowA = (size_t)(bm * 128 + ra) * K;
  const size_t rowB = (size_t)(bn * 64 + rb) * K;

  for (int kk = 0; kk < K; kk += 16) {
    float4 a0 = *(const float4*)(A + rowA + kk + ca);
    float4 a1 = *(const float4*)(A + rowA + kk + ca + 4);
    float4 b0 = *(const float4*)(Bw + rowB + kk + cb);
    __syncthreads();  // previous-tile reads done before overwrite
    As[ca + 0][ra] = a0.x; As[ca + 1][ra] = a0.y;
    As[ca + 2][ra] = a0.z; As[ca + 3][ra] = a0.w;
    As[ca + 4][ra] = a1.x; As[ca + 5][ra] = a1.y;
    As[ca + 6][ra] = a1.z; As[ca + 7][ra] = a1.w;
    Bs[cb + 0][rb] = b0.x; Bs[cb + 1][rb] = b0.y;
    Bs[cb + 2][rb] = b0.z; Bs[cb + 3][rb] = b0.w;
    __syncthreads();  // tile ready
#pragma unroll
    for (int k = 0; k < 16; ++k) {   // ascending k — order is the whole point
      float ar[8], br[4];
#pragma unroll
      for (int i = 0; i < 8; ++i) ar[i] = As[k][ty * 8 + i];
#pragma unroll
      for (int j = 0; j < 4; ++j) br[j] = Bs[k][tx * 4 + j];
#pragma unroll
      for (int i = 0; i < 8; ++i)
#pragma unroll
        for (int j = 0; j < 4; ++j)
          pacc[i][j] = __builtin_fmaf(ar[i], br[j], pacc[i][j]);
    }
    int e = kk >> 4;  // this 16-block's index; panel ends after it if mask bit set
    bool bnd = (e < 64) ? ((pm0 >> e) & 1ull) : ((pm1 >> (e - 64)) & 1ull);
    if (bnd) {
#pragma unroll
      for (int i = 0; i < 8; ++i)
#pragma unroll
        for (int j = 0; j < 4; ++j) {
          creg[i][j] = fencef(creg[i][j] + pacc[i][j]);  // C += panel (one f32 add)
          pacc[i][j] = 0.0f;
        }
    }
  }
  float* Cb = C + (size_t)(bm * 128 + ty * 8) * N + bn * 64 + tx * 4;
#pragma unroll
  for (int i = 0; i < 8; ++i)
#pragma unroll
    for (int j = 0; j < 4; ++j)
      Cb[(size_t)i * N + j] = creg[i][j];
}

// ---------- FLOAT32 LIF over TC steps, np f32 semantics, fenced per op ----------
__global__ void lif_chunk(const float* __restrict__ Z, const float* __restrict__ bias,
                          float* __restrict__ stC, float* __restrict__ stV,
                          float* __restrict__ stU, float* __restrict__ Sout,
                          float* __restrict__ accB, float* __restrict__ Out,
                          int ncol, int first, int last) {
  int gid = blockIdx.x * 256 + threadIdx.x;  // b*ncol + n
  int n = gid & (ncol - 1);
  float bn = bias[n];
  float c, v, u, s, acc;
  if (first) {
    c = 0.f; v = 0.f; u = 0.f; s = 0.f; acc = 0.f;
  } else {
    c = stC[gid]; v = stV[gid]; u = stU[gid];
    s = (v > 0.5f) ? 1.0f : 0.0f;              // bitwise-identical recompute
    acc = accB ? accB[gid] : 0.f;
  }
  size_t strideT = (size_t)B_ * (size_t)ncol;
#pragma unroll
  for (int tt = 0; tt < TC; ++tt) {
    float z = Z[(size_t)tt * strideT + gid];
    float t1 = fencef(c * 0.5f);
    float t2 = fencef(t1 + z);
    c = fencef(t2 + bn);                       // ((c*0.5)+z)+b — np order
    float w1 = fencef(1.0f - s);
    float w2 = fencef(v * w1);
    float w3 = fencef(0.021f * s);
    float vv = fencef(w2 + w3);                // post-reset v'
    float w4 = fencef(s * 0.132f);
    float uu = fencef(u + w4);                 // post-reset u'
    float q1 = fencef(vv * vv);
    float q2 = fencef(q1 - vv);
    float q3 = fencef(q2 - uu);
    float dv = fencef(q3 + c);
    float r1 = fencef(-0.172f * vv);
    float r2 = fencef(0.529f * uu);
    float du = fencef(r1 + r2);
    v = fencef(vv + dv);
    u = fencef(uu + du);
    s = (v > 0.5f) ? 1.0f : 0.0f;
    if (Sout) Sout[(size_t)tt * strideT + gid] = s;
    acc = fencef(acc + s);                     // exact small integer
  }
  stC[gid] = c; stV[gid] = v; stU[gid] = u;
  if (accB) accB[gid] = acc;
  if (Out && last) Out[gid] = acc * 0.0625f;   // acc/16 exact
}

// K-panel boundaries: fixed width Q (512 divides both K's cleanly; halving
// branch never triggers).
static void mkmask(int K, int Q, unsigned long long& m0, unsigned long long& m1) {
  m0 = 0; m1 = 0;
  int ls = 0;
  while (ls < K) {
    int rem = K - ls, L;
    if (rem >= 2 * Q) L = Q;
    else if (rem > Q) L = ((rem / 2 + 15) / 16) * 16;
    else L = rem;
    ls += L;
    int idx = ls / 16 - 1;
    if (idx < 64) m0 |= 1ull << idx;
    else m1 |= 1ull << (idx - 64);
  }
}

extern "C" void kernel_launch(void* const* d_in, const int* in_sizes, int n_in,
                              void* d_out, int out_size, void* d_ws, size_t ws_size,
                              hipStream_t stream) {
  const float* X  = (const float*)d_in[0];
  const float* W0 = (const float*)d_in[1];
  const float* b0 = (const float*)d_in[2];
  const float* W1 = (const float*)d_in[3];
  const float* b1 = (const float*)d_in[4];
  const float* W2 = (const float*)d_in[5];
  const float* b2 = (const float*)d_in[6];
  float* Out = (float*)d_out;
  char* ws = (char*)d_ws;
  constexpr size_t MB = 1024ull * 1024ull;
  // workspace layout — peak 72 MB (proven in-bounds since round 4)
  float* Xt   = (float*)(ws);              // [2048][2048] f32 = 16 MB
  float* Z    = (float*)(ws + 16 * MB);    // [2048][1024] f32 =  8 MB (per-layer reuse)
  float* S0c  = (float*)(ws + 24 * MB);    // [2048][1024] f32 =  8 MB
  float* S1c  = (float*)(ws + 32 * MB);    // [2048][1024] f32 =  8 MB
  float* st0c = (float*)(ws + 40 * MB);    // [1024*1024] f32 = 4 MB each
  float* st0v = (float*)(ws + 44 * MB);
  float* st0u = (float*)(ws + 48 * MB);
  float* st1c = (float*)(ws + 52 * MB);
  float* st1v = (float*)(ws + 56 * MB);
  float* st1u = (float*)(ws + 60 * MB);
  float* st2c = (float*)(ws + 64 * MB);    // [1024*512] f32 = 2 MB each
  float* st2v = (float*)(ws + 66 * MB);
  float* st2u = (float*)(ws + 68 * MB);
  float* accB = (float*)(ws + 70 * MB);    // [1024*512] f32 = 2 MB

  unsigned long long mA0, mA1, mB0, mB1;
  mkmask(IN_, GEMM_Q, mA0, mA1);   // K=2048: 4 panels of 512
  mkmask(H0_, GEMM_Q, mB0, mB1);   // K=1024: 2 panels of 512

  for (int ci = 0; ci < NCHUNK; ++ci) {
    int first = (ci == 0) ? 1 : 0;
    int last = (ci == NCHUNK - 1) ? 1 : 0;
    transpose_x2<<<(B_ * IN_) / 256, 256, 0, stream>>>(X, Xt, ci * TC);
    // layer 0: Z = Xt @ W0^T (panel-ordered f32, Q=512)
    gemm_obs<<<(TC * B_ / 128) * (H0_ / 64), 256, 0, stream>>>(
        Xt, W0, Z, H0_ / 64, IN_, H0_, mA0, mA1);
    lif_chunk<<<(B_ * H0_) / 256, 256, 0, stream>>>(Z, b0, st0c, st0v, st0u,
                                                    S0c, nullptr, nullptr, H0_, first, 0);
    // layer 1
    gemm_obs<<<(TC * B_ / 128) * (H1_ / 64), 256, 0, stream>>>(
        S0c, W1, Z, H1_ / 64, H0_, H1_, mB0, mB1);
    lif_chunk<<<(B_ * H1_) / 256, 256, 0, stream>>>(Z, b1, st1c, st1v, st1u,
                                                    S1c, nullptr, nullptr, H1_, first, 0);
    // layer 2 -> acc, last chunk writes Out
    gemm_obs<<<(TC * B_ / 128) * (OUT_ / 64), 256, 0, stream>>>(
        S1c, W2, Z, OUT_ / 64, H1_, OUT_, mB0, mB1);
    lif_chunk<<<(B_ * OUT_) / 256, 256, 0, stream>>>(Z, b2, st2c, st2v, st2u,
                                                     nullptr, accB, Out, OUT_, first, last);
  }
}

// Round 17
// 1968.495 us; speedup vs baseline: 1.4932x; 1.4932x over previous
//
#include <hip/hip_runtime.h>
#include <stdint.h>

#pragma clang fp contract(off)

constexpr int B_ = 1024, IN_ = 2048, H0_ = 1024, H1_ = 1024, OUT_ = 512;
constexpr int TC = 2;        // timesteps per chunk
constexpr int NCHUNK = 8;    // 16 / TC
constexpr int PQ = 512;      // K-panel width (bitwise-verified in round 16)

// Arithmetic fence: forces the f32 value to materialize — kills FMA contraction
// and reassociation across this point even under -ffp-contract=fast.
static __device__ __forceinline__ float fencef(float x) {
  asm volatile("" : "+v"(x));
  return x;
}

// ---------- transpose chunk: X[b][i][t0+tc] -> Xt[tc*B + b][i] (f32) ----------
__global__ void transpose_x2(const float* __restrict__ X, float* __restrict__ Xt, int t0) {
  int idx = blockIdx.x * 256 + threadIdx.x;  // b*IN + i
  int b = idx >> 11, i = idx & (IN_ - 1);
  float2 v = *(const float2*)(X + (size_t)idx * 16 + t0);
  Xt[(size_t)b * IN_ + i] = v.x;
  Xt[(size_t)(B_ + b) * IN_ + i] = v.y;
}

// ---------- f32 NT GEMM, ONE 512-panel per block (order-preserving K-split) ----
// Panel p of C[M][N]: pacc = sum_{k=512p..512p+511} fma(A[m,k], B[n,k], pacc),
// single accumulator, ascending k, f32 FMA — bitwise-identical chain to the
// round-16 passing kernel. Panels are combined left-associatively in the LIF
// kernel (also bitwise-identical to round 16's creg loop).
// BM=128, BN=64, BK=32; 256 threads; 8x4 micro-tile.
__global__ __launch_bounds__(256) void gemm_panel(
    const float* __restrict__ A, const float* __restrict__ Bw,
    float* __restrict__ ZP, size_t pstride, int Ntiles, int K, int N) {
  __shared__ float As[32][132];  // k-major, padded
  __shared__ float Bs[32][68];

  // bijective XCD swizzle (all grids here are multiples of 8)
  int bid = blockIdx.x, cpx = gridDim.x >> 3;
  int wg = (bid & 7) * cpx + (bid >> 3);
  int tpp = (gridDim.x / ((K + PQ - 1) / PQ));     // tiles per panel = Mt*Nt
  int p = wg / tpp, r = wg - p * tpp;
  int bm = r / Ntiles, bn = r - bm * Ntiles;

  int tid = threadIdx.x;
  int ra = tid >> 1, ca = (tid & 1) * 16;  // A staging: row 0..127, 16-col half
  int rb = tid >> 2, cb = (tid & 3) * 8;   // B staging: row 0..63, 8-col quarter
  int tx = tid & 15, ty = tid >> 4;        // micro-tile: cols tx*4.., rows ty*8..

  float acc[8][4] = {};   // THE panel chain accumulator (init 0, ascending k)
  const size_t rowA = (size_t)(bm * 128 + ra) * K + p * PQ;
  const size_t rowB = (size_t)(bn * 64 + rb) * K + p * PQ;

  for (int kk = 0; kk < PQ; kk += 32) {
    float4 a0 = *(const float4*)(A + rowA + kk + ca);
    float4 a1 = *(const float4*)(A + rowA + kk + ca + 4);
    float4 a2 = *(const float4*)(A + rowA + kk + ca + 8);
    float4 a3 = *(const float4*)(A + rowA + kk + ca + 12);
    float4 b0 = *(const float4*)(Bw + rowB + kk + cb);
    float4 b1 = *(const float4*)(Bw + rowB + kk + cb + 4);
    __syncthreads();  // previous-tile reads done before overwrite
    As[ca + 0][ra] = a0.x;  As[ca + 1][ra] = a0.y;
    As[ca + 2][ra] = a0.z;  As[ca + 3][ra] = a0.w;
    As[ca + 4][ra] = a1.x;  As[ca + 5][ra] = a1.y;
    As[ca + 6][ra] = a1.z;  As[ca + 7][ra] = a1.w;
    As[ca + 8][ra] = a2.x;  As[ca + 9][ra] = a2.y;
    As[ca + 10][ra] = a2.z; As[ca + 11][ra] = a2.w;
    As[ca + 12][ra] = a3.x; As[ca + 13][ra] = a3.y;
    As[ca + 14][ra] = a3.z; As[ca + 15][ra] = a3.w;
    Bs[cb + 0][rb] = b0.x;  Bs[cb + 1][rb] = b0.y;
    Bs[cb + 2][rb] = b0.z;  Bs[cb + 3][rb] = b0.w;
    Bs[cb + 4][rb] = b1.x;  Bs[cb + 5][rb] = b1.y;
    Bs[cb + 6][rb] = b1.z;  Bs[cb + 7][rb] = b1.w;
    __syncthreads();  // tile ready
#pragma unroll
    for (int k = 0; k < 32; ++k) {   // ascending k — order is frozen
      float ar[8], br[4];
#pragma unroll
      for (int i = 0; i < 8; ++i) ar[i] = As[k][ty * 8 + i];
#pragma unroll
      for (int j = 0; j < 4; ++j) br[j] = Bs[k][tx * 4 + j];
#pragma unroll
      for (int i = 0; i < 8; ++i)
#pragma unroll
        for (int j = 0; j < 4; ++j)
          acc[i][j] = __builtin_fmaf(ar[i], br[j], acc[i][j]);
    }
  }
  float* Cb = ZP + p * pstride + (size_t)(bm * 128 + ty * 8) * N + bn * 64 + tx * 4;
#pragma unroll
  for (int i = 0; i < 8; ++i)
#pragma unroll
    for (int j = 0; j < 4; ++j)
      Cb[(size_t)i * N + j] = acc[i][j];
}

// ---------- FLOAT32 LIF over TC steps + in-order panel combine, fenced ----------
// z = (((0 + P0) + P1) + ...) — bitwise-identical to round 16's creg loop.
template <int NP>
__global__ void lif_chunk(const float* __restrict__ ZP, size_t pstride,
                          const float* __restrict__ bias,
                          float* __restrict__ stC, float* __restrict__ stV,
                          float* __restrict__ stU, float* __restrict__ Sout,
                          float* __restrict__ accB, float* __restrict__ Out,
                          int ncol, int first, int last) {
  int gid = blockIdx.x * 256 + threadIdx.x;  // b*ncol + n
  int n = gid & (ncol - 1);
  float bn = bias[n];
  float c, v, u, s, acc;
  if (first) {
    c = 0.f; v = 0.f; u = 0.f; s = 0.f; acc = 0.f;
  } else {
    c = stC[gid]; v = stV[gid]; u = stU[gid];
    s = (v > 0.5f) ? 1.0f : 0.0f;              // bitwise-identical recompute
    acc = accB ? accB[gid] : 0.f;
  }
  size_t strideT = (size_t)B_ * (size_t)ncol;
#pragma unroll
  for (int tt = 0; tt < TC; ++tt) {
    float z = 0.f;
#pragma unroll
    for (int p = 0; p < NP; ++p)
      z = fencef(z + ZP[(size_t)p * pstride + (size_t)tt * strideT + gid]);
    float t1 = fencef(c * 0.5f);
    float t2 = fencef(t1 + z);
    c = fencef(t2 + bn);                       // ((c*0.5)+z)+b — np order
    float w1 = fencef(1.0f - s);
    float w2 = fencef(v * w1);
    float w3 = fencef(0.021f * s);
    float vv = fencef(w2 + w3);                // post-reset v'
    float w4 = fencef(s * 0.132f);
    float uu = fencef(u + w4);                 // post-reset u'
    float q1 = fencef(vv * vv);
    float q2 = fencef(q1 - vv);
    float q3 = fencef(q2 - uu);
    float dv = fencef(q3 + c);
    float r1 = fencef(-0.172f * vv);
    float r2 = fencef(0.529f * uu);
    float du = fencef(r1 + r2);
    v = fencef(vv + dv);
    u = fencef(uu + du);
    s = (v > 0.5f) ? 1.0f : 0.0f;
    if (Sout) Sout[(size_t)tt * strideT + gid] = s;
    acc = fencef(acc + s);                     // exact small integer
  }
  stC[gid] = c; stV[gid] = v; stU[gid] = u;
  if (accB) accB[gid] = acc;
  if (Out && last) Out[gid] = acc * 0.0625f;   // acc/16 exact
}

extern "C" void kernel_launch(void* const* d_in, const int* in_sizes, int n_in,
                              void* d_out, int out_size, void* d_ws, size_t ws_size,
                              hipStream_t stream) {
  const float* X  = (const float*)d_in[0];
  const float* W0 = (const float*)d_in[1];
  const float* b0 = (const float*)d_in[2];
  const float* W1 = (const float*)d_in[3];
  const float* b1 = (const float*)d_in[4];
  const float* W2 = (const float*)d_in[5];
  const float* b2 = (const float*)d_in[6];
  float* Out = (float*)d_out;
  char* ws = (char*)d_ws;
  constexpr size_t MB = 1024ull * 1024ull;
  // workspace layout — peak 96 MB (110 MB proven in-bounds since round 4)
  float* Xt   = (float*)(ws);              // [2048][2048] f32 = 16 MB
  float* ZP   = (float*)(ws + 16 * MB);    // 4 panels x [2048][1024] f32 = 32 MB
  float* S0c  = (float*)(ws + 48 * MB);    // [2048][1024] f32 =  8 MB
  float* S1c  = (float*)(ws + 56 * MB);    // [2048][1024] f32 =  8 MB
  float* st0c = (float*)(ws + 64 * MB);    // [1024*1024] f32 = 4 MB each
  float* st0v = (float*)(ws + 68 * MB);
  float* st0u = (float*)(ws + 72 * MB);
  float* st1c = (float*)(ws + 76 * MB);
  float* st1v = (float*)(ws + 80 * MB);
  float* st1u = (float*)(ws + 84 * MB);
  float* st2c = (float*)(ws + 88 * MB);    // [1024*512] f32 = 2 MB each
  float* st2v = (float*)(ws + 90 * MB);
  float* st2u = (float*)(ws + 92 * MB);
  float* accB = (float*)(ws + 94 * MB);    // [1024*512] f32 = 2 MB

  const size_t psH = (size_t)(TC * B_) * H0_;  // panel stride, N=1024 layers
  const size_t psO = (size_t)(TC * B_) * OUT_; // panel stride, N=512 layer

  for (int ci = 0; ci < NCHUNK; ++ci) {
    int first = (ci == 0) ? 1 : 0;
    int last = (ci == NCHUNK - 1) ? 1 : 0;
    transpose_x2<<<(B_ * IN_) / 256, 256, 0, stream>>>(X, Xt, ci * TC);
    // layer 0: K=2048 -> 4 panels; grid = 4 * 16 * 16 = 1024 blocks
    gemm_panel<<<4 * (TC * B_ / 128) * (H0_ / 64), 256, 0, stream>>>(
        Xt, W0, ZP, psH, H0_ / 64, IN_, H0_);
    lif_chunk<4><<<(B_ * H0_) / 256, 256, 0, stream>>>(
        ZP, psH, b0, st0c, st0v, st0u, S0c, nullptr, nullptr, H0_, first, 0);
    // layer 1: K=1024 -> 2 panels; grid = 2 * 16 * 16 = 512 blocks
    gemm_panel<<<2 * (TC * B_ / 128) * (H1_ / 64), 256, 0, stream>>>(
        S0c, W1, ZP, psH, H1_ / 64, H0_, H1_);
    lif_chunk<2><<<(B_ * H1_) / 256, 256, 0, stream>>>(
        ZP, psH, b1, st1c, st1v, st1u, S1c, nullptr, nullptr, H1_, first, 0);
    // layer 2: K=1024 -> 2 panels; grid = 2 * 16 * 8 = 256 blocks
    gemm_panel<<<2 * (TC * B_ / 128) * (OUT_ / 64), 256, 0, stream>>>(
        S1c, W2, ZP, psO, OUT_ / 64, H1_, OUT_);
    lif_chunk<2><<<(B_ * OUT_) / 256, 256, 0, stream>>>(
        ZP, psO, b2, st2c, st2v, st2u, nullptr, accB, Out, OUT_, first, last);
  }
}